// Round 2
// baseline (249.776 us; speedup 1.0000x reference)
//
#include <hip/hip_runtime.h>

#define B_   4
#define C_   256
#define C8_  32
#define N_   4096
#define JS   2                 // key split: js0 -> fp32 in d_out, js1 -> bf16 pnum1
#define NJ   (N_ / JS)         // 2048 keys per attn block
#define NTILE (NJ / 32)        // 64 j-tiles per attn block
#define BCN  ((size_t)B_ * C_ * N_)   // 4,194,304

typedef __attribute__((ext_vector_type(8))) short bf16x8;
typedef __attribute__((ext_vector_type(4))) float f32x4;

__device__ inline short f2bf(float f) {
    union { float f; unsigned u; } v; v.f = f;
    unsigned r = v.u + 0x7FFFu + ((v.u >> 16) & 1u);   // RNE
    return (short)(r >> 16);
}
__device__ inline float bf2f(short s) {
    union { unsigned u; float f; } v; v.u = ((unsigned)(unsigned short)s) << 16;
    return v.f;
}

// ---------------------------------------------------------------------------
// Kernel 0: prep. blocks [0,1024): transpose x -> xT[B][N][C] bf16 (64x64
// tiles via LDS). blocks [1024,1064): W fp32 -> Wall[320][256] bf16
// (rows 0-31 Wq, 32-63 Wk, 64-319 Wv). block 1064: bias gather ball[320].
// ---------------------------------------------------------------------------
__global__ __launch_bounds__(256) void prep_kernel(
    const float* __restrict__ x,
    const float* __restrict__ Wq, const float* __restrict__ bq,
    const float* __restrict__ Wk, const float* __restrict__ bk,
    const float* __restrict__ Wv, const float* __restrict__ bv,
    short* __restrict__ xT, short* __restrict__ Wall, float* __restrict__ ball)
{
    const int blk = blockIdx.x;
    const int t   = threadIdx.x;
    if (blk < 1024) {
        __shared__ float tile[64 * 67];
        const int b   = blk >> 8;
        const int rem = blk & 255;
        const int c0  = (rem >> 6) << 6;
        const int n0  = (rem & 63) << 6;
        const float* xb = x + ((size_t)b * C_ + c0) * N_ + n0;
        #pragma unroll
        for (int i = 0; i < 4; i++) {
            int e = t + i * 256;                 // 1024 float4 = 64 rows x 16
            int c = e >> 4, n4 = (e & 15) * 4;
            float4 v = *(const float4*)(xb + (size_t)c * N_ + n4);
            float* dst = &tile[c * 67 + n4];
            dst[0] = v.x; dst[1] = v.y; dst[2] = v.z; dst[3] = v.w;
        }
        __syncthreads();
        short* xo = xT + ((size_t)b * N_ + n0) * C_ + c0;
        #pragma unroll
        for (int i = 0; i < 4; i++) {
            int e = t + i * 256;
            int n = e >> 4, c4 = (e & 15) * 4;
            short4 s;
            s.x = f2bf(tile[(c4 + 0) * 67 + n]);
            s.y = f2bf(tile[(c4 + 1) * 67 + n]);
            s.z = f2bf(tile[(c4 + 2) * 67 + n]);
            s.w = f2bf(tile[(c4 + 3) * 67 + n]);
            *(short4*)(xo + (size_t)n * C_ + c4) = s;
        }
    } else if (blk < 1064) {
        const int base = (blk - 1024) * 2048 + t * 8;   // 40*2048 = 320*256
        const int r = base >> 8, cc = base & 255;
        const float* src = (r < 32) ? &Wq[r * C_ + cc]
                         : (r < 64) ? &Wk[(r - 32) * C_ + cc]
                                    : &Wv[(r - 64) * C_ + cc];
        const float4 a  = *(const float4*)src;
        const float4 b4 = *(const float4*)(src + 4);
        short4 s1, s2;
        s1.x = f2bf(a.x);  s1.y = f2bf(a.y);  s1.z = f2bf(a.z);  s1.w = f2bf(a.w);
        s2.x = f2bf(b4.x); s2.y = f2bf(b4.y); s2.z = f2bf(b4.z); s2.w = f2bf(b4.w);
        *(short4*)&Wall[base]     = s1;
        *(short4*)&Wall[base + 4] = s2;
    } else {
        for (int i = t; i < 320; i += 256)
            ball[i] = (i < 32) ? bq[i] : (i < 64) ? bk[i - 32] : bv[i - 64];
    }
}

// ---------------------------------------------------------------------------
// Kernel 1: MFMA projections. out[co][p] = sum_c W[co][c] x[c][p], co in 0..319.
// Grid (N/64, 2, B), 256 thr. Wave = 16 px, 10 co-tiles, K=256 in 8 steps.
// ---------------------------------------------------------------------------
__global__ __launch_bounds__(256, 2) void proj_kernel(
    const short* __restrict__ xT, const short* __restrict__ Wall,
    const float* __restrict__ ball,
    short* __restrict__ qws, short* __restrict__ kws, short* __restrict__ vws)
{
    const int n0    = blockIdx.x * 64;
    const int split = blockIdx.y;
    const int b     = blockIdx.z;
    const int t     = threadIdx.x;
    const int w     = t >> 6, lane = t & 63, l16 = lane & 15, quad = lane >> 4;
    const int n     = n0 + w * 16 + l16;

    bf16x8 bfr[8];
    const short* xrow = xT + ((size_t)b * N_ + n) * C_;
    #pragma unroll
    for (int k = 0; k < 8; k++) bfr[k] = *(const bf16x8*)(xrow + k * 32 + quad * 8);

    f32x4 acc[10];
    #pragma unroll
    for (int i = 0; i < 10; i++) acc[i] = (f32x4){0.f, 0.f, 0.f, 0.f};

    const int gct0 = split * 10;
    #pragma unroll
    for (int k = 0; k < 8; k++) {
        #pragma unroll
        for (int ct = 0; ct < 10; ct++) {
            const bf16x8 af = *(const bf16x8*)
                &Wall[(size_t)((gct0 + ct) * 16 + l16) * C_ + k * 32 + quad * 8];
            acc[ct] = __builtin_amdgcn_mfma_f32_16x16x32_bf16(af, bfr[k], acc[ct], 0, 0, 0);
        }
    }

    #pragma unroll
    for (int ct = 0; ct < 10; ct++) {
        const int gct = gct0 + ct;
        const int cb  = gct * 16 + quad * 4;
        float v0 = acc[ct][0] + ball[cb + 0];
        float v1 = acc[ct][1] + ball[cb + 1];
        float v2 = acc[ct][2] + ball[cb + 2];
        float v3 = acc[ct][3] + ball[cb + 3];
        if (gct < 2) {
            short4 s; s.x = f2bf(v0); s.y = f2bf(v1); s.z = f2bf(v2); s.w = f2bf(v3);
            *(short4*)&qws[((size_t)b * N_ + n) * C8_ + cb] = s;
        } else if (gct < 4) {
            short4 s; s.x = f2bf(v0); s.y = f2bf(v1); s.z = f2bf(v2); s.w = f2bf(v3);
            *(short4*)&kws[((size_t)b * N_ + n) * C8_ + (cb - 32)] = s;
        } else {
            const int c = cb - 64;
            vws[((size_t)b * C_ + c + 0) * N_ + n] = f2bf(v0);
            vws[((size_t)b * C_ + c + 1) * N_ + n] = f2bf(v1);
            vws[((size_t)b * C_ + c + 2) * N_ + n] = f2bf(v2);
            vws[((size_t)b * C_ + c + 3) * N_ + n] = f2bf(v3);
        }
    }
}

// ---------------------------------------------------------------------------
// Kernel 2: MFMA flash attention, 2-way key split, NO atomics.
// v3: 32-q blocks -> grid 1024 = 4 blocks/CU (latency-bound fix; v2 proved
// LDS BW was not the limit: 4x less LDS traffic, 13x fewer conflicts, same
// time, all pipes <25%).
//   - 4 waves C-split (wave w owns c in [64w,64w+64)); QK duty split:
//     wave w computes the single 16x16 S^T fragment (jh=w&1, qh=w>>1).
//     1 QK + 8 PV MFMA per wave per tile; acc = 32 VGPR -> fits 4 waves/EU.
//   - V fragments direct from global (per-(b,js) V-half is 1 MB, maps 1:1
//     onto an XCD under blk%8 -> L2-resident), prefetched 1 tile ahead,
//     issued AFTER the barrier (its vmcnt(0) drain would serialize them).
//   - P exchange via LDS [2][32 q][32 j] bf16, 16B-unit XOR swizzle
//     (u ^= (q>>1)&3): writes uniform 4/bank, b128 reads uniform 8/bank.
//   - Denominator partials per (js,jh) -> pl[4][16384].
// ---------------------------------------------------------------------------
__global__ __launch_bounds__(256, 4) void attn_kernel(
    const short* __restrict__ qws, const short* __restrict__ kws,
    const short* __restrict__ vws,
    float* __restrict__ out, short* __restrict__ pnum1, float* __restrict__ pl)
{
    __shared__ short Plds[2][32 * 32];   // 2 x 2 KB, swizzled 64 B rows

    const int blk = blockIdx.x;
    const int b   = blk & 3;
    const int js  = (blk >> 2) & 1;
    const int qc  = blk >> 3;            // 0..127, 32 q each
    const int t   = threadIdx.x;
    const int w   = t >> 6, lane = t & 63, l16 = lane & 15, quad = lane >> 4;
    const int jh  = w & 1;               // j half this wave computes in QK
    const int qh  = w >> 1;              // q half this wave computes in QK
    const int q   = qc * 32 + qh * 16 + l16;   // QK-duty q row for this lane

    const bf16x8 qf = *(const bf16x8*)&qws[((size_t)b * N_ + q) * C8_ + quad * 8];

    f32x4 acc[4][2];
    #pragma unroll
    for (int i = 0; i < 4; i++)
        #pragma unroll
        for (int j = 0; j < 2; j++) acc[i][j] = (f32x4){0.f, 0.f, 0.f, 0.f};
    float lsum = 0.f;

    const short* kbase = kws + ((size_t)b * N_ + js * NJ + jh * 16) * C8_;
    const short* vbase = vws + ((size_t)b * C_ + w * 64) * (size_t)N_ + js * NJ;

    // swizzle helpers: 16B unit u' = u ^ ((row>>1)&3); row&15 == l16 for both
    // the write row (qh*16+l16) and read rows (qt*16+l16), so fr is shared.
    const int fr = (l16 >> 1) & 3;
    const int wo = (qh * 16 + l16) * 32
                 + (((jh * 2 + (quad >> 1)) ^ fr) << 3) + ((quad & 1) << 2);
    const int ro = l16 * 32 + ((quad ^ fr) << 3);        // + qt*512

    // prologue: tile 0 K fragment + V fragments
    bf16x8 kf = *(const bf16x8*)(kbase + (size_t)l16 * C8_ + quad * 8);
    bf16x8 vf[4];
    #pragma unroll
    for (int ct = 0; ct < 4; ct++)
        vf[ct] = *(const bf16x8*)(vbase + (size_t)(ct * 16 + l16) * N_ + quad * 8);

    for (int tile = 0; tile < NTILE; ++tile) {
        const int buf = tile & 1;

        // QK^T: this wave's 16x16 fragment S^T[j=jh*16+quad*4+r][q=qh*16+l16]
        f32x4 s = __builtin_amdgcn_mfma_f32_16x16x32_bf16(
            kf, qf, (f32x4){0.f, 0.f, 0.f, 0.f}, 0, 0, 0);

        // softmax numerator (no max: scores bounded ~O(3) at this scale)
        float pe[4];
        #pragma unroll
        for (int r = 0; r < 4; r++) { pe[r] = __expf(s[r]); lsum += pe[r]; }

        short4 pa;
        pa.x = f2bf(pe[0]); pa.y = f2bf(pe[1]); pa.z = f2bf(pe[2]); pa.w = f2bf(pe[3]);
        *(short4*)&Plds[buf][wo] = pa;

        __syncthreads();                       // publish P[buf]

        // prefetch next tile's K + V fragments (post-sync: the barrier's
        // vmcnt(0) drain must not wait on these)
        const int tn = (tile + 1 < NTILE) ? tile + 1 : tile;
        bf16x8 kn = *(const bf16x8*)(kbase + (size_t)(tn * 32 + l16) * C8_ + quad * 8);
        bf16x8 vn[4];
        {
            const short* vb = vbase + tn * 32;
            #pragma unroll
            for (int ct = 0; ct < 4; ct++)
                vn[ct] = *(const bf16x8*)(vb + (size_t)(ct * 16 + l16) * N_ + quad * 8);
        }

        // PV: wave w's 64 c x all 32 q
        #pragma unroll
        for (int qt = 0; qt < 2; ++qt) {
            const bf16x8 pf = *(const bf16x8*)&Plds[buf][qt * 512 + ro];
            #pragma unroll
            for (int ct = 0; ct < 4; ++ct)
                acc[ct][qt] = __builtin_amdgcn_mfma_f32_16x16x32_bf16(
                    vf[ct], pf, acc[ct][qt], 0, 0, 0);
        }

        kf = kn;
        #pragma unroll
        for (int ct = 0; ct < 4; ct++) vf[ct] = vn[ct];
    }

    // denominator partial over this wave's (js,jh) j-range for q
    lsum += __shfl_xor(lsum, 16, 64);
    lsum += __shfl_xor(lsum, 32, 64);
    if (quad == 0) pl[(size_t)(js * 2 + jh) * 16384 + (size_t)b * N_ + q] = lsum;

    // numerator partial: js0 -> fp32 into out, js1 -> bf16 into pnum1
    const int qq = qc * 32 + l16;
    if (js == 0) {
        float* ob = out + (size_t)b * C_ * N_;
        #pragma unroll
        for (int ct = 0; ct < 4; ++ct)
            #pragma unroll
            for (int qt = 0; qt < 2; ++qt)
                #pragma unroll
                for (int r = 0; r < 4; ++r) {
                    const int c = w * 64 + ct * 16 + quad * 4 + r;
                    ob[(size_t)c * N_ + qq + qt * 16] = acc[ct][qt][r];
                }
    } else {
        short* pb1 = pnum1 + (size_t)b * C_ * N_;
        #pragma unroll
        for (int ct = 0; ct < 4; ++ct)
            #pragma unroll
            for (int qt = 0; qt < 2; ++qt)
                #pragma unroll
                for (int r = 0; r < 4; ++r) {
                    const int c = w * 64 + ct * 16 + quad * 4 + r;
                    pb1[(size_t)c * N_ + qq + qt * 16] = f2bf(acc[ct][qt][r]);
                }
    }
}

// ---------------------------------------------------------------------------
// Kernel 3: linv = 1/sum(pl[0..3]).  Kernel 4: out = g*(out+pnum1)*linv + x.
// ---------------------------------------------------------------------------
__global__ __launch_bounds__(256) void lred_kernel(
    const float* __restrict__ pl, float* __restrict__ linv)
{
    const int i = blockIdx.x * 256 + threadIdx.x;   // over B*N = 16384
    linv[i] = 1.0f / (pl[i] + pl[16384 + i] + pl[32768 + i] + pl[49152 + i]);
}

__global__ __launch_bounds__(256) void combine_kernel(
    const short* __restrict__ pnum1, const float* __restrict__ linv,
    const float* __restrict__ x, const float* __restrict__ gamma,
    float* __restrict__ out)
{
    const size_t i4 = ((size_t)blockIdx.x * 256 + threadIdx.x) * 4;   // < BCN
    const float4 nv = *(const float4*)(out + i4);
    const short4 n1 = *(const short4*)(pnum1 + i4);
    const float4 xv = *(const float4*)(x + i4);
    const int   bn  = (int)((i4 >> 20) * 4096 + (i4 & 4095));         // b*N + n
    const float4 lv = *(const float4*)(linv + bn);
    const float g0 = gamma[0];
    float4 o;
    o.x = g0 * ((nv.x + bf2f(n1.x)) * lv.x) + xv.x;
    o.y = g0 * ((nv.y + bf2f(n1.y)) * lv.y) + xv.y;
    o.z = g0 * ((nv.z + bf2f(n1.z)) * lv.z) + xv.z;
    o.w = g0 * ((nv.w + bf2f(n1.w)) * lv.w) + xv.w;
    *(float4*)(out + i4) = o;
}

extern "C" void kernel_launch(void* const* d_in, const int* in_sizes, int n_in,
                              void* d_out, int out_size, void* d_ws, size_t ws_size,
                              hipStream_t stream)
{
    const float* x     = (const float*)d_in[0];
    const float* Wq    = (const float*)d_in[1];
    const float* bq    = (const float*)d_in[2];
    const float* Wk    = (const float*)d_in[3];
    const float* bk    = (const float*)d_in[4];
    const float* Wv    = (const float*)d_in[5];
    const float* bv    = (const float*)d_in[6];
    const float* gamma = (const float*)d_in[7];
    float* out = (float*)d_out;

    // ws layout, 18.63 MiB total (<= 20 MB proven-safe in R1).
    // pnum1 overlaps xT: xT dead after proj_kernel, pnum1 written by attn.
    char* base = (char*)d_ws;
    short* vws   = (short*)(base);                      // 8 MB  [B][256][N] @ 0x0
    short* qws   = (short*)(base + 0x800000);           // 1 MB  [B][N][32]
    short* kws   = (short*)(base + 0x900000);           // 1 MB  [B][N][32]
    float* pl    = (float*)(base + 0xA00000);           // 256 KB [4][B*N]
    float* linv  = (float*)(base + 0xA40000);           // 64 KB
    short* Wall  = (short*)(base + 0xA50000);           // 160 KB
    float* ball  = (float*)(base + 0xA78000);           // 1.25 KB
    short* xT    = (short*)(base + 0xA80000);           // 8 MB  [B][N][256]
    short* pnum1 = (short*)(base + 0xA80000);           // 8 MB  [B][256][N] (over xT)

    prep_kernel<<<1065, 256, 0, stream>>>(x, Wq, bq, Wk, bk, Wv, bv, xT, Wall, ball);
    proj_kernel<<<dim3(N_ / 64, 2, B_), 256, 0, stream>>>(xT, Wall, ball, qws, kws, vws);
    attn_kernel<<<1024, 256, 0, stream>>>(qws, kws, vws, out, pnum1, pl);
    lred_kernel<<<64, 256, 0, stream>>>(pl, linv);
    combine_kernel<<<4096, 256, 0, stream>>>(pnum1, linv, x, gamma, out);
}

// Round 3
// 192.537 us; speedup vs baseline: 1.2973x; 1.2973x over previous
//
#include <hip/hip_runtime.h>

#define B_   4
#define C_   256
#define C8_  32
#define N_   4096
#define JS   2                 // key split: js0 -> fp32 in d_out, js1 -> bf16 pnum1
#define NJ   (N_ / JS)         // 2048 keys per attn block
#define KB2  128               // j per tile (v4: 4x bigger -> 16 barriers not 64)
#define NT2  (NJ / KB2)        // 16 j-tiles per attn block
#define BCN  ((size_t)B_ * C_ * N_)   // 4,194,304

typedef __attribute__((ext_vector_type(8))) short bf16x8;
typedef __attribute__((ext_vector_type(4))) float f32x4;

__device__ inline short f2bf(float f) {
    union { float f; unsigned u; } v; v.f = f;
    unsigned r = v.u + 0x7FFFu + ((v.u >> 16) & 1u);   // RNE
    return (short)(r >> 16);
}
__device__ inline float bf2f(short s) {
    union { unsigned u; float f; } v; v.u = ((unsigned)(unsigned short)s) << 16;
    return v.f;
}

// ---------------------------------------------------------------------------
// Kernel 0: prep. blocks [0,1024): transpose x -> xT[B][N][C] bf16 (64x64
// tiles via LDS). blocks [1024,1064): W fp32 -> Wall[320][256] bf16
// (rows 0-31 Wq, 32-63 Wk, 64-319 Wv). block 1064: bias gather ball[320].
// ---------------------------------------------------------------------------
__global__ __launch_bounds__(256) void prep_kernel(
    const float* __restrict__ x,
    const float* __restrict__ Wq, const float* __restrict__ bq,
    const float* __restrict__ Wk, const float* __restrict__ bk,
    const float* __restrict__ Wv, const float* __restrict__ bv,
    short* __restrict__ xT, short* __restrict__ Wall, float* __restrict__ ball)
{
    const int blk = blockIdx.x;
    const int t   = threadIdx.x;
    if (blk < 1024) {
        __shared__ float tile[64 * 67];
        const int b   = blk >> 8;
        const int rem = blk & 255;
        const int c0  = (rem >> 6) << 6;
        const int n0  = (rem & 63) << 6;
        const float* xb = x + ((size_t)b * C_ + c0) * N_ + n0;
        #pragma unroll
        for (int i = 0; i < 4; i++) {
            int e = t + i * 256;                 // 1024 float4 = 64 rows x 16
            int c = e >> 4, n4 = (e & 15) * 4;
            float4 v = *(const float4*)(xb + (size_t)c * N_ + n4);
            float* dst = &tile[c * 67 + n4];
            dst[0] = v.x; dst[1] = v.y; dst[2] = v.z; dst[3] = v.w;
        }
        __syncthreads();
        short* xo = xT + ((size_t)b * N_ + n0) * C_ + c0;
        #pragma unroll
        for (int i = 0; i < 4; i++) {
            int e = t + i * 256;
            int n = e >> 4, c4 = (e & 15) * 4;
            short4 s;
            s.x = f2bf(tile[(c4 + 0) * 67 + n]);
            s.y = f2bf(tile[(c4 + 1) * 67 + n]);
            s.z = f2bf(tile[(c4 + 2) * 67 + n]);
            s.w = f2bf(tile[(c4 + 3) * 67 + n]);
            *(short4*)(xo + (size_t)n * C_ + c4) = s;
        }
    } else if (blk < 1064) {
        const int base = (blk - 1024) * 2048 + t * 8;   // 40*2048 = 320*256
        const int r = base >> 8, cc = base & 255;
        const float* src = (r < 32) ? &Wq[r * C_ + cc]
                         : (r < 64) ? &Wk[(r - 32) * C_ + cc]
                                    : &Wv[(r - 64) * C_ + cc];
        const float4 a  = *(const float4*)src;
        const float4 b4 = *(const float4*)(src + 4);
        short4 s1, s2;
        s1.x = f2bf(a.x);  s1.y = f2bf(a.y);  s1.z = f2bf(a.z);  s1.w = f2bf(a.w);
        s2.x = f2bf(b4.x); s2.y = f2bf(b4.y); s2.z = f2bf(b4.z); s2.w = f2bf(b4.w);
        *(short4*)&Wall[base]     = s1;
        *(short4*)&Wall[base + 4] = s2;
    } else {
        for (int i = t; i < 320; i += 256)
            ball[i] = (i < 32) ? bq[i] : (i < 64) ? bk[i - 32] : bv[i - 64];
    }
}

// ---------------------------------------------------------------------------
// Kernel 1: MFMA projections. out[co][p] = sum_c W[co][c] x[c][p], co in 0..319.
// Grid (N/64, 2, B), 256 thr. Wave = 16 px, 10 co-tiles, K=256 in 8 steps.
// ---------------------------------------------------------------------------
__global__ __launch_bounds__(256, 2) void proj_kernel(
    const short* __restrict__ xT, const short* __restrict__ Wall,
    const float* __restrict__ ball,
    short* __restrict__ qws, short* __restrict__ kws, short* __restrict__ vws)
{
    const int n0    = blockIdx.x * 64;
    const int split = blockIdx.y;
    const int b     = blockIdx.z;
    const int t     = threadIdx.x;
    const int w     = t >> 6, lane = t & 63, l16 = lane & 15, quad = lane >> 4;
    const int n     = n0 + w * 16 + l16;

    bf16x8 bfr[8];
    const short* xrow = xT + ((size_t)b * N_ + n) * C_;
    #pragma unroll
    for (int k = 0; k < 8; k++) bfr[k] = *(const bf16x8*)(xrow + k * 32 + quad * 8);

    f32x4 acc[10];
    #pragma unroll
    for (int i = 0; i < 10; i++) acc[i] = (f32x4){0.f, 0.f, 0.f, 0.f};

    const int gct0 = split * 10;
    #pragma unroll
    for (int k = 0; k < 8; k++) {
        #pragma unroll
        for (int ct = 0; ct < 10; ct++) {
            const bf16x8 af = *(const bf16x8*)
                &Wall[(size_t)((gct0 + ct) * 16 + l16) * C_ + k * 32 + quad * 8];
            acc[ct] = __builtin_amdgcn_mfma_f32_16x16x32_bf16(af, bfr[k], acc[ct], 0, 0, 0);
        }
    }

    #pragma unroll
    for (int ct = 0; ct < 10; ct++) {
        const int gct = gct0 + ct;
        const int cb  = gct * 16 + quad * 4;
        float v0 = acc[ct][0] + ball[cb + 0];
        float v1 = acc[ct][1] + ball[cb + 1];
        float v2 = acc[ct][2] + ball[cb + 2];
        float v3 = acc[ct][3] + ball[cb + 3];
        if (gct < 2) {
            short4 s; s.x = f2bf(v0); s.y = f2bf(v1); s.z = f2bf(v2); s.w = f2bf(v3);
            *(short4*)&qws[((size_t)b * N_ + n) * C8_ + cb] = s;
        } else if (gct < 4) {
            short4 s; s.x = f2bf(v0); s.y = f2bf(v1); s.z = f2bf(v2); s.w = f2bf(v3);
            *(short4*)&kws[((size_t)b * N_ + n) * C8_ + (cb - 32)] = s;
        } else {
            const int c = cb - 64;
            vws[((size_t)b * C_ + c + 0) * N_ + n] = f2bf(v0);
            vws[((size_t)b * C_ + c + 1) * N_ + n] = f2bf(v1);
            vws[((size_t)b * C_ + c + 2) * N_ + n] = f2bf(v2);
            vws[((size_t)b * C_ + c + 3) * N_ + n] = f2bf(v3);
        }
    }
}

// ---------------------------------------------------------------------------
// Kernel 2: MFMA flash attention, v4. Evidence from v0/v2/v3: per-tile cost
// is a FIXED ~3000 cy (barrier round-trip + 1-deep load chains) regardless of
// work; so amortize it: KVBLK=128 -> 16 barriers/block instead of 64, with
// 72 MFMA + 32 exp per wave per barrier.
//   - 64-q blocks, grid 512 = exactly 2 blocks/CU (proven co-resident fit).
//   - QK q-split: wave w owns q in [16w,16w+16) x all 128 j (8 MFMA).
//   - PV C-split: wave w owns c in [64w,64w+64) x all 64 q (64 MFMA, 4 ks).
//   - P exchange: LDS [2][64 q][128 j] bf16 (2x16 KB), 16B-unit XOR swizzle
//     u' = u ^ (row&7): both write and read are 2-way max (free).
//   - V streamed from global per-ks (4x bf16x8), issued 1-2 phases early;
//     K for tile+1 prefetched into the same kf regs right after QK.
//   - One __syncthreads per tile; P double-buffer makes WAR safe.
// Numerator MFMA chain order identical to v0/v2 (same ascending K=32 chunks).
// ---------------------------------------------------------------------------
__global__ __launch_bounds__(256, 2) void attn_kernel(
    const short* __restrict__ qws, const short* __restrict__ kws,
    const short* __restrict__ vws,
    float* __restrict__ out, short* __restrict__ pnum1, float* __restrict__ pl)
{
    __shared__ short Plds[2][64 * 128];   // 2 x 16 KB

    const int blk = blockIdx.x;
    const int b   = blk & 3;
    const int js  = (blk >> 2) & 1;
    const int qc  = blk >> 3;            // 0..63
    const int t   = threadIdx.x;
    const int w   = t >> 6, lane = t & 63, l16 = lane & 15, quad = lane >> 4;
    const int q   = qc * 64 + w * 16 + l16;   // QK-duty q row for this lane

    const bf16x8 qf = *(const bf16x8*)&qws[((size_t)b * N_ + q) * C8_ + quad * 8];

    f32x4 acc[4][4];
    #pragma unroll
    for (int i = 0; i < 4; i++)
        #pragma unroll
        for (int j = 0; j < 4; j++) acc[i][j] = (f32x4){0.f, 0.f, 0.f, 0.f};
    float lsum = 0.f;

    const short* kbase = kws + ((size_t)b * N_ + js * NJ) * C8_;
    const short* vbase = vws + ((size_t)b * C_ + w * 64) * (size_t)N_ + js * NJ;

    // swizzle: 16B unit u' = u ^ (row&7); row&7 == l16&7 for write row
    // (w*16+l16) and all read rows (qt*16+l16).
    const int swz   = l16 & 7;
    const int prowW = (w * 16 + l16) * 128 + (quad & 1) * 4;   // + u'*8

    // prologue: kf for tile 0 (8 j-frags x K=32)
    bf16x8 kf[8];
    #pragma unroll
    for (int jf = 0; jf < 8; jf++)
        kf[jf] = *(const bf16x8*)(kbase + (size_t)(jf * 16 + l16) * C8_ + quad * 8);

    for (int tile = 0; tile < NT2; ++tile) {
        const int buf = tile & 1;
        const short* vb = vbase + tile * KB2;

        // V for ks0, ks1: issue early (latency hides under QK+softmax+barrier)
        bf16x8 vf0[4], vf1[4];
        #pragma unroll
        for (int ct = 0; ct < 4; ct++)
            vf0[ct] = *(const bf16x8*)(vb + (size_t)(ct * 16 + l16) * N_ + 0 * 32 + quad * 8);
        #pragma unroll
        for (int ct = 0; ct < 4; ct++)
            vf1[ct] = *(const bf16x8*)(vb + (size_t)(ct * 16 + l16) * N_ + 1 * 32 + quad * 8);

        // QK^T: S^T[j][q] for this wave's 16 q over 128 j
        f32x4 s[8];
        #pragma unroll
        for (int jf = 0; jf < 8; jf++)
            s[jf] = __builtin_amdgcn_mfma_f32_16x16x32_bf16(
                kf[jf], qf, (f32x4){0.f, 0.f, 0.f, 0.f}, 0, 0, 0);

        // prefetch next tile's K into the same regs (lifetime of old kf ends
        // at the MFMAs above); consumed only after this tile's PV.
        if (tile + 1 < NT2) {
            const short* kb = kbase + (size_t)((tile + 1) * KB2) * C8_;
            #pragma unroll
            for (int jf = 0; jf < 8; jf++)
                kf[jf] = *(const bf16x8*)(kb + (size_t)(jf * 16 + l16) * C8_ + quad * 8);
        }

        // softmax numerator (no max: scores bounded ~O(3) at this scale),
        // pack to bf16, publish to LDS
        #pragma unroll
        for (int jf = 0; jf < 8; jf++) {
            float p0 = __expf(s[jf][0]); float p1 = __expf(s[jf][1]);
            float p2 = __expf(s[jf][2]); float p3 = __expf(s[jf][3]);
            lsum += p0 + p1 + p2 + p3;
            short4 pa; pa.x = f2bf(p0); pa.y = f2bf(p1); pa.z = f2bf(p2); pa.w = f2bf(p3);
            const int u = (jf * 2 + (quad >> 1)) ^ swz;
            *(short4*)&Plds[buf][prowW + u * 8] = pa;
        }

        __syncthreads();                       // publish P[buf]

        // V ks2 issued now; ks3 after the ks0 MFMAs
        bf16x8 vf2[4];
        #pragma unroll
        for (int ct = 0; ct < 4; ct++)
            vf2[ct] = *(const bf16x8*)(vb + (size_t)(ct * 16 + l16) * N_ + 2 * 32 + quad * 8);

        // PV ks0
        #pragma unroll
        for (int qt = 0; qt < 4; ++qt) {
            const bf16x8 pf = *(const bf16x8*)
                &Plds[buf][(qt * 16 + l16) * 128 + ((0 * 4 + quad) ^ swz) * 8];
            #pragma unroll
            for (int ct = 0; ct < 4; ++ct)
                acc[ct][qt] = __builtin_amdgcn_mfma_f32_16x16x32_bf16(
                    vf0[ct], pf, acc[ct][qt], 0, 0, 0);
        }

        bf16x8 vf3[4];
        #pragma unroll
        for (int ct = 0; ct < 4; ct++)
            vf3[ct] = *(const bf16x8*)(vb + (size_t)(ct * 16 + l16) * N_ + 3 * 32 + quad * 8);

        // PV ks1
        #pragma unroll
        for (int qt = 0; qt < 4; ++qt) {
            const bf16x8 pf = *(const bf16x8*)
                &Plds[buf][(qt * 16 + l16) * 128 + ((1 * 4 + quad) ^ swz) * 8];
            #pragma unroll
            for (int ct = 0; ct < 4; ++ct)
                acc[ct][qt] = __builtin_amdgcn_mfma_f32_16x16x32_bf16(
                    vf1[ct], pf, acc[ct][qt], 0, 0, 0);
        }

        // PV ks2
        #pragma unroll
        for (int qt = 0; qt < 4; ++qt) {
            const bf16x8 pf = *(const bf16x8*)
                &Plds[buf][(qt * 16 + l16) * 128 + ((2 * 4 + quad) ^ swz) * 8];
            #pragma unroll
            for (int ct = 0; ct < 4; ++ct)
                acc[ct][qt] = __builtin_amdgcn_mfma_f32_16x16x32_bf16(
                    vf2[ct], pf, acc[ct][qt], 0, 0, 0);
        }

        // PV ks3
        #pragma unroll
        for (int qt = 0; qt < 4; ++qt) {
            const bf16x8 pf = *(const bf16x8*)
                &Plds[buf][(qt * 16 + l16) * 128 + ((3 * 4 + quad) ^ swz) * 8];
            #pragma unroll
            for (int ct = 0; ct < 4; ++ct)
                acc[ct][qt] = __builtin_amdgcn_mfma_f32_16x16x32_bf16(
                    vf3[ct], pf, acc[ct][qt], 0, 0, 0);
        }
    }

    // denominator partial for this wave's q over its full j half
    lsum += __shfl_xor(lsum, 16, 64);
    lsum += __shfl_xor(lsum, 32, 64);
    if (quad == 0) pl[(size_t)js * 16384 + (size_t)b * N_ + q] = lsum;

    // numerator partial: js0 -> fp32 into out, js1 -> bf16 into pnum1
    const int qq = qc * 64 + l16;
    if (js == 0) {
        float* ob = out + (size_t)b * C_ * N_;
        #pragma unroll
        for (int ct = 0; ct < 4; ++ct)
            #pragma unroll
            for (int qt = 0; qt < 4; ++qt)
                #pragma unroll
                for (int r = 0; r < 4; ++r) {
                    const int c = w * 64 + ct * 16 + quad * 4 + r;
                    ob[(size_t)c * N_ + qq + qt * 16] = acc[ct][qt][r];
                }
    } else {
        short* pb1 = pnum1 + (size_t)b * C_ * N_;
        #pragma unroll
        for (int ct = 0; ct < 4; ++ct)
            #pragma unroll
            for (int qt = 0; qt < 4; ++qt)
                #pragma unroll
                for (int r = 0; r < 4; ++r) {
                    const int c = w * 64 + ct * 16 + quad * 4 + r;
                    pb1[(size_t)c * N_ + qq + qt * 16] = f2bf(acc[ct][qt][r]);
                }
    }
}

// ---------------------------------------------------------------------------
// Kernel 3: linv = 1/(pl0+pl1).  Kernel 4: out = g*(out + pnum1)*linv + x.
// ---------------------------------------------------------------------------
__global__ __launch_bounds__(256) void lred_kernel(
    const float* __restrict__ pl, float* __restrict__ linv)
{
    const int i = blockIdx.x * 256 + threadIdx.x;   // over B*N = 16384
    linv[i] = 1.0f / (pl[i] + pl[16384 + i]);
}

__global__ __launch_bounds__(256) void combine_kernel(
    const short* __restrict__ pnum1, const float* __restrict__ linv,
    const float* __restrict__ x, const float* __restrict__ gamma,
    float* __restrict__ out)
{
    const size_t i4 = ((size_t)blockIdx.x * 256 + threadIdx.x) * 4;   // < BCN
    const float4 nv = *(const float4*)(out + i4);
    const short4 n1 = *(const short4*)(pnum1 + i4);
    const float4 xv = *(const float4*)(x + i4);
    const int   bn  = (int)((i4 >> 20) * 4096 + (i4 & 4095));         // b*N + n
    const float4 lv = *(const float4*)(linv + bn);
    const float g0 = gamma[0];
    float4 o;
    o.x = g0 * ((nv.x + bf2f(n1.x)) * lv.x) + xv.x;
    o.y = g0 * ((nv.y + bf2f(n1.y)) * lv.y) + xv.y;
    o.z = g0 * ((nv.z + bf2f(n1.z)) * lv.z) + xv.z;
    o.w = g0 * ((nv.w + bf2f(n1.w)) * lv.w) + xv.w;
    *(float4*)(out + i4) = o;
}

extern "C" void kernel_launch(void* const* d_in, const int* in_sizes, int n_in,
                              void* d_out, int out_size, void* d_ws, size_t ws_size,
                              hipStream_t stream)
{
    const float* x     = (const float*)d_in[0];
    const float* Wq    = (const float*)d_in[1];
    const float* bq    = (const float*)d_in[2];
    const float* Wk    = (const float*)d_in[3];
    const float* bk    = (const float*)d_in[4];
    const float* Wv    = (const float*)d_in[5];
    const float* bv    = (const float*)d_in[6];
    const float* gamma = (const float*)d_in[7];
    float* out = (float*)d_out;

    // ws layout, 18.4 MiB total (<= 20 MB proven-safe in R1).
    // pnum1 overlaps xT: xT dead after proj_kernel, pnum1 written by attn.
    char* base = (char*)d_ws;
    short* vws   = (short*)(base);                      // 8 MB  [B][256][N] @ 0x0
    short* qws   = (short*)(base + 0x800000);           // 1 MB  [B][N][32]
    short* kws   = (short*)(base + 0x900000);           // 1 MB  [B][N][32]
    float* pl    = (float*)(base + 0xA00000);           // 128 KB [2][B*N]
    float* linv  = (float*)(base + 0xA20000);           // 64 KB
    short* Wall  = (short*)(base + 0xA30000);           // 160 KB
    float* ball  = (float*)(base + 0xA58000);           // 1.25 KB
    short* xT    = (short*)(base + 0xA60000);           // 8 MB  [B][N][256]
    short* pnum1 = (short*)(base + 0xA60000);           // 8 MB  [B][256][N] (over xT)

    prep_kernel<<<1065, 256, 0, stream>>>(x, Wq, bq, Wk, bk, Wv, bv, xT, Wall, ball);
    proj_kernel<<<dim3(N_ / 64, 2, B_), 256, 0, stream>>>(xT, Wall, ball, qws, kws, vws);
    attn_kernel<<<512, 256, 0, stream>>>(qws, kws, vws, out, pnum1, pl);
    lred_kernel<<<64, 256, 0, stream>>>(pl, linv);
    combine_kernel<<<4096, 256, 0, stream>>>(pnum1, linv, x, gamma, out);
}